// Round 23
// baseline (517.208 us; speedup 1.0000x reference)
//
#include <hip/hip_runtime.h>
#include <cstdint>
#include <cstddef>

typedef unsigned short u16;
typedef __attribute__((ext_vector_type(8))) short short8;
typedef __attribute__((ext_vector_type(4))) float f32x4;

#define DEV __device__ __forceinline__

DEV float bf2f(u16 v) { union { unsigned u; float f; } x; x.u = ((unsigned)v) << 16; return x.f; }
DEV u16 f2bf(float f) {
  union { float f; unsigned u; } x; x.f = f;
  unsigned r = x.u + 0x7fffu + ((x.u >> 16) & 1u);
  return (u16)(r >> 16);
}

DEV void gload_lds16(const void* g, void* l) {
  __builtin_amdgcn_global_load_lds((const __attribute__((address_space(1))) void*)g,
                                   (__attribute__((address_space(3))) void*)l, 16, 0, 0);
}

#define BARRIER __builtin_amdgcn_s_barrier()
#define VM0 asm volatile("s_waitcnt vmcnt(0)" ::: "memory")
#define VM4 asm volatile("s_waitcnt vmcnt(4)" ::: "memory")

// ---------- RMSNorm row body: f32 row (2048) -> bf16 ----------
DEV void rmsnorm_row(const float* __restrict__ x, const float* __restrict__ scale,
                     u16* __restrict__ out, int row, int tid, float* red)
{
  const float* xr = x + (size_t)row * 2048;
  const float4 v0 = *(const float4*)&xr[tid * 8];
  const float4 v1 = *(const float4*)&xr[tid * 8 + 4];
  float ss = v0.x * v0.x + v0.y * v0.y + v0.z * v0.z + v0.w * v0.w +
             v1.x * v1.x + v1.y * v1.y + v1.z * v1.z + v1.w * v1.w;
#pragma unroll
  for (int d = 32; d > 0; d >>= 1) ss += __shfl_down(ss, d);
  if ((tid & 63) == 0) red[tid >> 6] = ss;
  __syncthreads();
  const float tot = red[0] + red[1] + red[2] + red[3];
  const float inv = rsqrtf(tot * (1.f / 2048.f) + 1e-6f);
  const float* sc = scale + tid * 8;
  short8 ov;
  ov[0] = (short)f2bf(v0.x * inv * sc[0]); ov[1] = (short)f2bf(v0.y * inv * sc[1]);
  ov[2] = (short)f2bf(v0.z * inv * sc[2]); ov[3] = (short)f2bf(v0.w * inv * sc[3]);
  ov[4] = (short)f2bf(v1.x * inv * sc[4]); ov[5] = (short)f2bf(v1.y * inv * sc[5]);
  ov[6] = (short)f2bf(v1.z * inv * sc[6]); ov[7] = (short)f2bf(v1.w * inv * sc[7]);
  *(short8*)&out[(size_t)row * 2048 + tid * 8] = ov;
}

// ---------- 64x64 transpose tile: f32 (R x C) -> bf16 (C x R) ----------
// mode 0: row j -> j. mode 1 (gate) / 2 (up): SwiGLU-interleaved row
// (256-row granularity): perm(j) = (j>>7)*256 + ((j>>5)&3)*64 + up*32 + (j&31)
DEV void transpose_tile(const float* __restrict__ in, u16* __restrict__ out,
                        int R, int C, int mode, int bx, int by, int bz,
                        int tid, float (&tile)[64][65])
{
  const int tx = tid & 31, ty = tid >> 5;   // (32, 8)
  const int c0 = bx * 64, r0 = by * 64;
  const float* inb = in + (size_t)bz * R * C;
  u16* outb = out + (size_t)bz * R * C;
#pragma unroll
  for (int i = 0; i < 8; ++i) {
    const int r = ty + i * 8;
    const float2 v = *(const float2*)&inb[(size_t)(r0 + r) * C + c0 + tx * 2];
    tile[r][tx * 2] = v.x;
    tile[r][tx * 2 + 1] = v.y;
  }
  __syncthreads();
#pragma unroll
  for (int i = 0; i < 8; ++i) {
    const int jj = ty + i * 8;
    const int j = c0 + jj;
    const int prow = mode ? ((j >> 7) * 256 + (((j >> 5) & 3) << 6) + ((mode == 2) << 5) + (j & 31))
                          : j;
    const unsigned a = f2bf(tile[tx * 2][jj]);
    const unsigned b = f2bf(tile[tx * 2 + 1][jj]);
    *(unsigned*)&outb[(size_t)prow * R + r0 + tx * 2] = a | (b << 16);
  }
}

// ---------- prep1: q/k/v/o transposes + bias concat + rmsnorm(ln1) ----------
// segments:
//   [0,1024)     q_w   (2,32,16) -> wqkv_t
//   [1024,1152)  k_w   (2,32,2)  -> wqkv_t + 2048*2048
//   [1152,1280)  v_w   (2,32,2)  -> wqkv_t + 2304*2048
//   [1280,2304)  o_w   (32,32,1) -> o_wt
//   [2304,2314)  concat_bias (10 x 256 threads)
//   [2314,6410)  rmsnorm ln1: x row (bid-2314) -> hbuf
__global__ __launch_bounds__(256) void prep_kernel(
    const float* __restrict__ q_w, const float* __restrict__ k_w,
    const float* __restrict__ v_w, const float* __restrict__ o_w,
    const float* __restrict__ qb, const float* __restrict__ kb,
    const float* __restrict__ vb,
    const float* __restrict__ x, const float* __restrict__ ln1,
    u16* __restrict__ wqkv_t, u16* __restrict__ o_wt,
    float* __restrict__ bias, u16* __restrict__ hbuf)
{
  __shared__ float tile[64][65];
  const int bid = (int)blockIdx.x;
  const int tid = threadIdx.x;
  if (bid < 1024) {
    transpose_tile(q_w, wqkv_t, 2048, 128, 0, bid & 1, (bid >> 1) & 31, bid >> 6, tid, tile);
  } else if (bid < 1152) {
    const int l = bid - 1024;
    transpose_tile(k_w, wqkv_t + 2048LL * 2048, 2048, 128, 0, l & 1, (l >> 1) & 31, l >> 6, tid, tile);
  } else if (bid < 1280) {
    const int l = bid - 1152;
    transpose_tile(v_w, wqkv_t + 2304LL * 2048, 2048, 128, 0, l & 1, (l >> 1) & 31, l >> 6, tid, tile);
  } else if (bid < 2304) {
    const int l = bid - 1280;
    transpose_tile(o_w, o_wt, 2048, 2048, 0, l & 31, l >> 5, 0, tid, tile);
  } else if (bid < 2314) {
    const int i = (bid - 2304) * 256 + tid;
    if (i < 2048) bias[i] = qb[i];
    else if (i < 2304) bias[i] = kb[i - 2048];
    else if (i < 2560) bias[i] = vb[i - 2304];
  } else {
    rmsnorm_row(x, ln1, hbuf, bid - 2314, tid, &tile[0][0]);
  }
}

// ---------- RMSNorm standalone (ln2) ----------
__global__ __launch_bounds__(256) void rmsnorm_kernel(
    const float* __restrict__ x, const float* __restrict__ scale, u16* __restrict__ out)
{
  __shared__ float red[4];
  rmsnorm_row(x, scale, out, blockIdx.x, threadIdx.x, red);
}

// ---------- qkv GEMM + packed prep2 (gate/up/down transposes) ----------
// blocks [0,640): qkv GEMM (128x128 tiles, MODE 3, GR=8, nwg=640 fixed).
// blocks [640,640+8256): gate (2752) / up (2752) / down (2752) transposes --
// memory-bound blocks that backfill CU slots as the compute-bound GEMM drains
// (their outputs gu_t/d_t are first read 3 dispatches later).
__global__ __launch_bounds__(256, 2) void qkv_prep2_kernel(
    const u16* __restrict__ A, const u16* __restrict__ Bt,
    u16* __restrict__ C, const float* __restrict__ aux,
    const float* __restrict__ gate_w, const float* __restrict__ up_w,
    const float* __restrict__ down_w,
    u16* __restrict__ gu_t, u16* __restrict__ d_t)
{
  constexpr int BM = 128, BN = 128, TB = 256, GR = 8;
  constexpr int MFRAG = 4, AISS = 4, BISS = 4, WN = 2;
  constexpr int NGEMM = 640;
  const int N = 2560, K = 2048, lda = 2048, ldb = 2048;
  __shared__ __align__(16) u16 As[2][BM * 64];
  __shared__ __align__(16) u16 Bs[3][BN * 64];

  const int tid = threadIdx.x;
  const int bid = (int)blockIdx.x;

  if (bid >= NGEMM) {
    auto& tile = *reinterpret_cast<float(*)[64][65]>(&As[0][0]);
    const int l = bid - NGEMM;
    if (l < 2752) {
      transpose_tile(gate_w, gu_t, 2048, 5504, 1, l % 86, l / 86, 0, tid, tile);
    } else if (l < 5504) {
      const int m = l - 2752;
      transpose_tile(up_w, gu_t, 2048, 5504, 2, m % 86, m / 86, 0, tid, tile);
    } else {
      const int m = l - 5504;
      transpose_tile(down_w, d_t, 5504, 2048, 0, m & 31, m >> 5, 0, tid, tile);
    }
    return;
  }

  const int wv = tid >> 6, lane = tid & 63, lo = lane & 15, hi = lane >> 4;
  const int wm = wv / WN, wn = wv % WN;

  const int id = (bid & 7) * (NGEMM >> 3) + (bid >> 3);   // XCD-chunked
  const int ncol = N / BN;
  const int rg = id % GR, cc = (id / GR) % ncol, gg = id / (GR * ncol);
  const int by = gg * GR + rg, bx = cc;
  const int row0 = by * BM, col0 = bx * BN;

  const f32x4 fz = {0.f, 0.f, 0.f, 0.f};
  f32x4 acc[MFRAG][4];
#pragma unroll
  for (int m = 0; m < MFRAG; ++m)
#pragma unroll
    for (int n = 0; n < 4; ++n) acc[m][n] = fz;

  const int nt = K >> 6;

  auto STAGE_A = [&](int kt, int ab) {
#pragma unroll
    for (int i = 0; i < AISS; ++i) {
      const int f = i * TB + tid;
      const int rp = f >> 3, sp = tid & 7;
      gload_lds16(A + (size_t)(row0 + rp) * lda + kt * 64 + ((sp ^ (rp & 7)) * 8),
                  (char*)&As[ab][0] + (i * TB + wv * 64) * 16);
    }
  };
  auto STAGE_B = [&](int kt, int bb) {
#pragma unroll
    for (int i = 0; i < BISS; ++i) {
      const int f = i * TB + tid;
      const int rp = f >> 3, sp = tid & 7;
      gload_lds16(Bt + (size_t)(col0 + rp) * ldb + kt * 64 + ((sp ^ (rp & 7)) * 8),
                  (char*)&Bs[bb][0] + (i * TB + wv * 64) * 16);
    }
  };

#define LDA8Q(ARR, BUF, S, G)                                                    \
  _Pragma("unroll")                                                              \
  for (int mt = 0; mt < 4; ++mt) {                                               \
    const int r = wm * (BM / 2) + ((G) * 4 + mt) * 16 + lo;                      \
    ARR[mt] = *(const short8*)&As[BUF][r * 64 + (((S) * 4 + hi) ^ (r & 7)) * 8]; \
  }
#define LDB8Q(ARR, BUF, S)                                                       \
  _Pragma("unroll")                                                              \
  for (int nn = 0; nn < 4; ++nn) {                                               \
    const int r = wn * 64 + nn * 16 + lo;                                        \
    ARR[nn] = *(const short8*)&Bs[BUF][r * 64 + (((S) * 4 + hi) ^ (r & 7)) * 8]; \
  }
#define MFMA16Q(AR, BR, G)                                                       \
  __builtin_amdgcn_s_setprio(1);                                                 \
  _Pragma("unroll")                                                              \
  for (int mt = 0; mt < 4; ++mt)                                                 \
    _Pragma("unroll")                                                            \
    for (int nn = 0; nn < 4; ++nn)                                               \
      acc[(G) * 4 + mt][nn] = __builtin_amdgcn_mfma_f32_16x16x32_bf16(           \
          AR[mt], BR[nn], acc[(G) * 4 + mt][nn], 0, 0, 0);                       \
  __builtin_amdgcn_s_setprio(0);

  STAGE_A(0, 0); STAGE_B(0, 0); STAGE_B(1, 1);
  VM4; BARRIER;

  int ab = 0, bcur = 0;
  for (int t = 0; t < nt; ++t) {
    const bool preA = (t + 1 < nt);
    const bool preB = (t + 2 < nt);
    const int bs2 = (bcur >= 1) ? bcur - 1 : 2;
    short8 a0[4], b0[4], a1[4], b1[4];
    LDA8Q(a0, ab, 0, 0); LDB8Q(b0, bcur, 0);
    LDA8Q(a1, ab, 1, 0); LDB8Q(b1, bcur, 1);
    if (preA) STAGE_A(t + 1, ab ^ 1);
    if (preB) STAGE_B(t + 2, bs2);
    MFMA16Q(a0, b0, 0);
    MFMA16Q(a1, b1, 0);
    if (preA) { if (preB) VM4; else VM0; }
    BARRIER;
    ab ^= 1;
    bcur = (bcur == 2) ? 0 : bcur + 1;
  }
#undef LDA8Q
#undef LDB8Q
#undef MFMA16Q

#pragma unroll
  for (int fm = 0; fm < MFRAG; ++fm) {
#pragma unroll
    for (int nn = 0; nn < 4; ++nn) {
      const int col = col0 + wn * 64 + nn * 16 + lo;
#pragma unroll
      for (int j = 0; j < 4; ++j) {
        const int row = row0 + wm * (BM / 2) + fm * 16 + hi * 4 + j;
        C[(size_t)row * N + col] = f2bf(acc[fm][nn][j] + aux[col]);
      }
    }
  }
}

// ---------- GEMM convoy, BK=64, TB threads (2M x (BN/64)N waves) ----------
// C(4096 x N) = A(4096 x K, lda) @ Bt(N x K, ldb)^T
// ONE barrier per K-tile (r15). A dbuf, B triple-buf, counted vmcnt(4); no
// explicit lgkm drain. Block order: XCD-chunked, then L2 super-tiled.
// 16x16x32 MFMA. Swizzle: slot = g ^ (row&7); linear LDS dest + inv-swz src.
// MODE 0: f32+bias[col]; 1: f32+aux[idx]; 2: bf16; 3: bf16+bias[col];
// MODE 4 (BM=256): SwiGLU-fused epilogue -> bf16 [4096 x N/2], ld = N/2.
template <int BM, int BN, int TB, int MODE, int GR>
__global__ __launch_bounds__(TB, 512 / TB) void gemm_conv_kernel(
    const u16* __restrict__ A, const u16* __restrict__ Bt,
    void* C, const float* __restrict__ aux, int N, int K, int lda, int ldb)
{
  constexpr int MFRAG = BM / 32;
  constexpr int AISS = BM * 8 / TB;
  constexpr int BISS = BN * 8 / TB;
  constexpr int WN = BN / 64;
  __shared__ __align__(16) u16 As[2][BM * 64];
  __shared__ __align__(16) u16 Bs[3][BN * 64];

  const int tid = threadIdx.x;
  const int wv = tid >> 6, lane = tid & 63, lo = lane & 15, hi = lane >> 4;
  const int wm = wv / WN, wn = wv % WN;

  const int nwg = (int)gridDim.x;
  const int id0 = (int)blockIdx.x;
  const int id = (id0 & 7) * (nwg >> 3) + (id0 >> 3);
  const int ncol = N / BN;
  const int rg = id % GR, cc = (id / GR) % ncol, gg = id / (GR * ncol);
  const int by = gg * GR + rg, bx = cc;
  const int row0 = by * BM, col0 = bx * BN;

  const f32x4 fz = {0.f, 0.f, 0.f, 0.f};
  f32x4 acc[MFRAG][4];
#pragma unroll
  for (int m = 0; m < MFRAG; ++m)
#pragma unroll
    for (int n = 0; n < 4; ++n) acc[m][n] = fz;

  const int nt = K >> 6;

  auto STAGE_A = [&](int kt, int ab) {
#pragma unroll
    for (int i = 0; i < AISS; ++i) {
      const int f = i * TB + tid;
      const int rp = f >> 3, sp = tid & 7;
      gload_lds16(A + (size_t)(row0 + rp) * lda + kt * 64 + ((sp ^ (rp & 7)) * 8),
                  (char*)&As[ab][0] + (i * TB + wv * 64) * 16);
    }
  };
  auto STAGE_B = [&](int kt, int bb) {
#pragma unroll
    for (int i = 0; i < BISS; ++i) {
      const int f = i * TB + tid;
      const int rp = f >> 3, sp = tid & 7;
      gload_lds16(Bt + (size_t)(col0 + rp) * ldb + kt * 64 + ((sp ^ (rp & 7)) * 8),
                  (char*)&Bs[bb][0] + (i * TB + wv * 64) * 16);
    }
  };

#define LDA8M(ARR, BUF, S, G)                                                    \
  _Pragma("unroll")                                                              \
  for (int mt = 0; mt < 4; ++mt) {                                               \
    const int r = wm * (BM / 2) + ((G) * 4 + mt) * 16 + lo;                      \
    ARR[mt] = *(const short8*)&As[BUF][r * 64 + (((S) * 4 + hi) ^ (r & 7)) * 8]; \
  }
#define LDB8M(ARR, BUF, S)                                                       \
  _Pragma("unroll")                                                              \
  for (int nn = 0; nn < 4; ++nn) {                                               \
    const int r = wn * 64 + nn * 16 + lo;                                        \
    ARR[nn] = *(const short8*)&Bs[BUF][r * 64 + (((S) * 4 + hi) ^ (r & 7)) * 8]; \
  }
#define MFMA16M(AR, BR, G)                                                       \
  __builtin_amdgcn_s_setprio(1);                                                 \
  _Pragma("unroll")                                                              \
  for (int mt = 0; mt < 4; ++mt)                                                 \
    _Pragma("unroll")                                                            \
    for (int nn = 0; nn < 4; ++nn)                                               \
      acc[(G) * 4 + mt][nn] = __builtin_amdgcn_mfma_f32_16x16x32_bf16(           \
          AR[mt], BR[nn], acc[(G) * 4 + mt][nn], 0, 0, 0);                       \
  __builtin_amdgcn_s_setprio(0);

  STAGE_A(0, 0); STAGE_B(0, 0); STAGE_B(1, 1);
  VM4; BARRIER;

  int ab = 0, bcur = 0;
  for (int t = 0; t < nt; ++t) {
    const bool preA = (t + 1 < nt);
    const bool preB = (t + 2 < nt);
    const int bs2 = (bcur >= 1) ? bcur - 1 : 2;
    if constexpr (BM == 256) {
      short8 a0[4], a1[4], b0[4], a2[4], a3[4], b1[4];
      LDA8M(a0, ab, 0, 0); LDA8M(a1, ab, 0, 1); LDB8M(b0, bcur, 0);
      LDA8M(a2, ab, 1, 0); LDA8M(a3, ab, 1, 1); LDB8M(b1, bcur, 1);
      if (preA) STAGE_A(t + 1, ab ^ 1);
      if (preB) STAGE_B(t + 2, bs2);
      MFMA16M(a0, b0, 0); MFMA16M(a1, b0, 1);
      MFMA16M(a2, b1, 0); MFMA16M(a3, b1, 1);
      if (preA) { if (preB) VM4; else VM0; }
      BARRIER;
    } else {
      short8 a0[4], b0[4], a1[4], b1[4];
      LDA8M(a0, ab, 0, 0); LDB8M(b0, bcur, 0);
      LDA8M(a1, ab, 1, 0); LDB8M(b1, bcur, 1);
      if (preA) STAGE_A(t + 1, ab ^ 1);
      if (preB) STAGE_B(t + 2, bs2);
      MFMA16M(a0, b0, 0);
      MFMA16M(a1, b1, 0);
      if (preA) { if (preB) VM4; else VM0; }
      BARRIER;
    }
    ab ^= 1;
    bcur = (bcur == 2) ? 0 : bcur + 1;
  }
#undef LDA8M
#undef LDB8M
#undef MFMA16M

  float* Cf = (float*)C;
  u16* Ch = (u16*)C;
  if constexpr (MODE == 4) {
    const int ldo = N >> 1;   // 5504
#pragma unroll
    for (int fm = 0; fm < MFRAG; ++fm) {
#pragma unroll
      for (int nn = 0; nn < 2; ++nn) {
        const int fcol = (col0 >> 1) + wn * 32 + nn * 16 + lo;
#pragma unroll
        for (int j = 0; j < 4; ++j) {
          const int row = row0 + wm * (BM / 2) + fm * 16 + hi * 4 + j;
          const float g = acc[fm][nn][j];
          const float u = acc[fm][nn + 2][j];
          const float sg = g / (1.f + __builtin_amdgcn_exp2f(-1.4426950408889634f * g));
          Ch[(size_t)row * ldo + fcol] = f2bf(sg * u);
        }
      }
    }
  } else {
#pragma unroll
    for (int fm = 0; fm < MFRAG; ++fm) {
#pragma unroll
      for (int nn = 0; nn < 4; ++nn) {
        const int col = col0 + wn * 64 + nn * 16 + lo;
#pragma unroll
        for (int j = 0; j < 4; ++j) {
          const int row = row0 + wm * (BM / 2) + fm * 16 + hi * 4 + j;
          const size_t idx = (size_t)row * N + col;
          const float v = acc[fm][nn][j];
          if (MODE == 0) Cf[idx] = v + aux[col];
          else if (MODE == 1) Cf[idx] = v + aux[idx];
          else if (MODE == 2) Ch[idx] = f2bf(v);
          else Ch[idx] = f2bf(v + aux[col]);
        }
      }
    }
  }
}

// ---------- fused RoPE q/k + V transpose: qkv bf16 (4096 x 2560) ----------
// per row: 1024 q-threads (2 elems each), 128 k-threads, 256 v-threads = 1408
// q scale = 1/sqrt(128) * log2(e)  (softmax done in exp2 domain)
__global__ __launch_bounds__(256) void rope_qkv_kernel(
    const u16* __restrict__ qkv, const int* __restrict__ pos,
    u16* __restrict__ Qb, u16* __restrict__ Kb, u16* __restrict__ Vt)
{
  const int idx = blockIdx.x * 256 + threadIdx.x;  // 4096*1408
  const int bt = idx / 1408;
  const int r = idx - bt * 1408;
  const int t = bt & 2047, b = bt >> 11;
  if (r < 1152) {
    const bool isq = r < 1024;
    const int rr = isq ? r : r - 1024;
    const int n = rr >> 6, hp = rr & 63;
    const u16* q = qkv + (size_t)bt * 2560 + (isq ? 0 : 2048) + n * 128 + hp;
    const float x1 = bf2f(q[0]);
    const float x2 = bf2f(q[64]);
    const float inv = exp2f((float)hp * (-19.931568569324174f / 64.f));
    const float ang = (float)pos[t] * inv;
    float s, c;
    sincosf(ang, &s, &c);
    const float sc = isq ? 0.08838834764831845f * 1.4426950408889634f : 1.f;
    const size_t base = isq ? (((size_t)(b * 16 + n) * 2048 + t) * 128 + hp)
                            : (((size_t)(b * 2 + n) * 2048 + t) * 128 + hp);
    u16* outp = isq ? Qb : Kb;
    outp[base] = f2bf((x1 * c - x2 * s) * sc);
    outp[base + 64] = f2bf((x2 * c + x1 * s) * sc);
  } else {
    const int rr = r - 1152;
    const int kh = rr >> 7, hh = rr & 127;
    Vt[((size_t)((b * 2 + kh) * 128 + hh)) * 2048 + t] =
        qkv[(size_t)bt * 2560 + 2304 + kh * 128 + hh];
  }
}

// ---------- flash attention, causal, GQA group 8 ----------
// 8 waves / 512 threads, Q-tile = 128 rows, KV-tile = 128 rows. LDS 160 KiB.
// Grid (bn=32, pair=8): all 8 pair-blocks of one head on one XCD (T1).
__global__ __launch_bounds__(512) void attn_kernel(
    const u16* __restrict__ Qb, const u16* __restrict__ Kb,
    const u16* __restrict__ Vt, u16* __restrict__ Out)
{
  __shared__ u16 Ks[2][128 * 128];   // 64 KB
  __shared__ u16 Vs[2][128 * 128];   // 64 KB
  __shared__ u16 Ps[8][16 * 128];    // 32 KB
  const int tid = threadIdx.x;
  const int wave = tid >> 6, lane = tid & 63, lo = lane & 15, hi = lane >> 4;
  const int bn = blockIdx.x;
  const int b = bn >> 4, n = bn & 15, kh = n >> 3;

  const f32x4 fz = {0.f, 0.f, 0.f, 0.f};
  const u16* kg = Kb + (size_t)(b * 2 + kh) * 2048 * 128;
  const u16* vg = Vt + (size_t)(b * 2 + kh) * 128 * 2048;

  auto STAGE = [&](int buf, int s0) {
#pragma unroll
    for (int i = 0; i < 4; ++i) {
      const int gk = i * 512 + tid;          // 2048 granules = 128 rows x 16
      const int rk = gk >> 4, gck = gk & 15;
      gload_lds16(kg + (size_t)(s0 + rk) * 128 + ((gck ^ (rk & 7)) * 8),
                  (char*)&Ks[buf][0] + (i * 512 + wave * 64) * 16);
      gload_lds16(vg + (size_t)rk * 2048 + s0 + ((gck ^ (rk & 7)) * 8),
                  (char*)&Vs[buf][0] + (i * 512 + wave * 64) * 16);
    }
  };

  auto processTile = [&](int q0) {
    const int nblk = q0 / 128 + 1;   // KV tiles of 128 covering [0, q0+128)
    const u16* qptr = Qb + ((size_t)((b * 16 + n) * 2048) + q0 + wave * 16 + lo) * 128;
    short8 qf[4];
#pragma unroll
    for (int kc = 0; kc < 4; ++kc) qf[kc] = *(const short8*)&qptr[kc * 32 + hi * 8];

    float m_r[4], l_r[4];
    f32x4 oacc[8];
#pragma unroll
    for (int j = 0; j < 4; ++j) { m_r[j] = -1e30f; l_r[j] = 0.f; }
#pragma unroll
    for (int ht = 0; ht < 8; ++ht) oacc[ht] = fz;

    __syncthreads();
    STAGE(0, 0);
    __syncthreads();

    int cur = 0;
    for (int sb = 0; sb < nblk; ++sb) {
      const int s0 = sb * 128;
      if (sb + 1 < nblk) STAGE(cur ^ 1, s0 + 128);

      float sall[8][4];
      __builtin_amdgcn_s_setprio(1);
#pragma unroll
      for (int st = 0; st < 8; ++st) {
        f32x4 s = fz;
#pragma unroll
        for (int kc = 0; kc < 4; ++kc) {
          const int row = st * 16 + lo;
          const int cb = (kc * 64 + hi * 16) ^ ((lo & 7) << 4);
          short8 kf = *(const short8*)&Ks[cur][row * 128 + (cb >> 1)];
          s = __builtin_amdgcn_mfma_f32_16x16x32_bf16(qf[kc], kf, s, 0, 0, 0);
        }
#pragma unroll
        for (int j = 0; j < 4; ++j) sall[st][j] = s[j];
      }
      __builtin_amdgcn_s_setprio(0);

      if (s0 + 128 > q0) {   // only the final tile needs the causal mask
#pragma unroll
        for (int st = 0; st < 8; ++st) {
          const int sg = s0 + st * 16 + lo;
#pragma unroll
          for (int j = 0; j < 4; ++j) {
            const int qg = q0 + wave * 16 + hi * 4 + j;
            if (sg > qg) sall[st][j] = -1e30f;
          }
        }
      }

      float tmax[4];
#pragma unroll
      for (int j = 0; j < 4; ++j) {
        float t = fmaxf(fmaxf(fmaxf(sall[0][j], sall[1][j]), fmaxf(sall[2][j], sall[3][j])),
                        fmaxf(fmaxf(sall[4][j], sall[5][j]), fmaxf(sall[6][j], sall[7][j])));
        t = fmaxf(t, __shfl_xor(t, 1));
        t = fmaxf(t, __shfl_xor(t, 2));
        t = fmaxf(t, __shfl_xor(t, 4));
        t = fmaxf(t, __shfl_xor(t, 8));
        tmax[j] = t;
      }
      const bool defer = __all((tmax[0] - m_r[0] <= 8.f) & (tmax[1] - m_r[1] <= 8.f) &
                               (tmax[2] - m_r[2] <= 8.f) & (tmax[3] - m_r[3] <= 8.f));
      if (!defer) {
        float alpha[4];
#pragma unroll
        for (int j = 0; j < 4; ++j) {
          const float mnew = fmaxf(m_r[j], tmax[j]);
          alpha[j] = __builtin_amdgcn_exp2f(m_r[j] - mnew);
          m_r[j] = mnew;
          l_r[j] *= alpha[j];
        }
#pragma unroll
        for (int ht = 0; ht < 8; ++ht) {
#pragma unroll
          for (int j = 0; j < 4; ++j) oacc[ht][j] *= alpha[j];
        }
      }

      float rsum[4] = {0.f, 0.f, 0.f, 0.f};
#pragma unroll
      for (int st = 0; st < 8; ++st) {
#pragma unroll
        for (int j = 0; j < 4; ++j) {
          const float p = __builtin_amdgcn_exp2f(sall[st][j] - m_r[j]);
          rsum[j] += p;
          const int row = hi * 4 + j;
          const int cbp = (st * 32 + lo * 2) ^ ((row & 7) << 4);
          Ps[wave][row * 128 + (cbp >> 1)] = f2bf(p);
        }
      }
#pragma unroll
      for (int j = 0; j < 4; ++j) {
        float rs = rsum[j];
        rs += __shfl_xor(rs, 1);
        rs += __shfl_xor(rs, 2);
        rs += __shfl_xor(rs, 4);
        rs += __shfl_xor(rs, 8);
        l_r[j] += rs;
      }

      asm volatile("s_waitcnt lgkmcnt(0)" ::: "memory");
      __builtin_amdgcn_sched_barrier(0);

      short8 pf[4];
#pragma unroll
      for (int s = 0; s < 4; ++s) {
        const int pcb = (s * 64 + hi * 16) ^ ((lo & 7) << 4);
        pf[s] = *(const short8*)&Ps[wave][lo * 128 + (pcb >> 1)];
      }
      __builtin_amdgcn_s_setprio(1);
#pragma unroll
      for (int ht = 0; ht < 8; ++ht) {
        const int row = ht * 16 + lo;
#pragma unroll
        for (int s = 0; s < 4; ++s) {
          const int cb = (s * 64 + hi * 16) ^ ((row & 7) << 4);
          const short8 vf = *(const short8*)&Vs[cur][row * 128 + (cb >> 1)];
          oacc[ht] = __builtin_amdgcn_mfma_f32_16x16x32_bf16(pf[s], vf, oacc[ht], 0, 0, 0);
        }
      }
      __builtin_amdgcn_s_setprio(0);

      if (sb + 1 < nblk) __syncthreads();
      cur ^= 1;
    }

#pragma unroll
    for (int j = 0; j < 4; ++j) {
      const float inv = 1.0f / l_r[j];
      const int trow = q0 + wave * 16 + hi * 4 + j;
      const size_t base = ((size_t)(b * 2048 + trow)) * 2048 + n * 128;
#pragma unroll
      for (int ht = 0; ht < 8; ++ht)
        Out[base + ht * 16 + lo] = f2bf(oacc[ht][j] * inv);
    }
  };

  processTile((int)(15 - blockIdx.y) * 128);
  processTile((int)blockIdx.y * 128);
}

extern "C" void kernel_launch(void* const* d_in, const int* in_sizes, int n_in,
                              void* d_out, int out_size, void* d_ws, size_t ws_size,
                              hipStream_t stream)
{
  const float* x      = (const float*)d_in[0];
  const int*   pos    = (const int*)d_in[1];
  const float* ln1    = (const float*)d_in[2];
  const float* q_w    = (const float*)d_in[3];
  const float* q_b    = (const float*)d_in[4];
  const float* k_w    = (const float*)d_in[5];
  const float* k_b    = (const float*)d_in[6];
  const float* v_w    = (const float*)d_in[7];
  const float* v_b    = (const float*)d_in[8];
  const float* o_w    = (const float*)d_in[9];
  const float* ln2    = (const float*)d_in[10];
  const float* gate_w = (const float*)d_in[11];
  const float* up_w   = (const float*)d_in[12];
  const float* down_w = (const float*)d_in[13];
  float* out = (float*)d_out;

  char* w = (char*)d_ws;
  u16* wqkv_t = (u16*)w;       w += 2560LL * 2048 * 2;   // (N*H+KH*H*2) x D, bf16
  u16* o_wt   = (u16*)w;       w += 2048LL * 2048 * 2;   // D x (N*H)
  u16* gu_t   = (u16*)w;       w += 11008LL * 2048 * 2;  // SwiGLU-interleaved [gate|up]
  u16* d_t    = (u16*)w;       w += 2048LL * 5504 * 2;   // D x I
  u16* hbuf   = (u16*)w;       w += 4096LL * 2048 * 2;   // h / h2 bf16
  float* bias_qkv = (float*)w; w += 2560 * 4;
  char* un = w;  // union region: phase1 (qkv/Qb/Kb/Vt/attn) then phase2 (fuse)
  u16*  qkv   = (u16*)un;                                              // 4096x2560 bf16
  u16*  Qb    = (u16*)(un + 41943040LL);                               // (B,N,T,H)
  u16*  Kb    = (u16*)(un + 41943040LL + 16777216LL);                  // (B,KH,T,H)
  u16*  Vt    = (u16*)(un + 41943040LL + 16777216LL + 2097152LL);      // (B,KH,H,T)
  u16*  attnb = (u16*)(un + 41943040LL + 16777216LL + 2097152LL + 2097152LL); // (B,T,N*H)
  u16*  fusebuf = (u16*)un;                                            // 4096x5504 bf16

  // prep1: q/k/v/o transposes + bias concat + rmsnorm(ln1)
  prep_kernel<<<6410, 256, 0, stream>>>(q_w, k_w, v_w, o_w, q_b, k_b, v_b,
                                        x, ln1, wqkv_t, o_wt, bias_qkv, hbuf);

  // qkv GEMM (640 blocks) + packed gate/up/down transposes (8256 blocks)
  qkv_prep2_kernel<<<8896, 256, 0, stream>>>(hbuf, wqkv_t, qkv, bias_qkv,
                                             gate_w, up_w, down_w, gu_t, d_t);

  // fused rope q/k + V transpose (1408 threads per (b,t) row)
  rope_qkv_kernel<<<22528, 256, 0, stream>>>(qkv, pos, Qb, Kb, Vt);
  // attention: grid (bn=32, pair=8), KV-tile = 128 rows, LDS 160 KiB
  attn_kernel<<<dim3(32, 8), 512, 0, stream>>>(Qb, Kb, Vt, attnb);
  // res = attn @ o_w^T + x -> out (f32): 128x128 tiles, GR=8 (K=2048)
  gemm_conv_kernel<128, 128, 256, 1, 8><<<512, 256, 0, stream>>>(attnb, o_wt, out, x, 2048, 2048, 2048, 2048);
  // ln2 -> h2 (reuse hbuf)
  rmsnorm_kernel<<<4096, 256, 0, stream>>>(out, ln2, hbuf);
  // gate+up merged + SwiGLU-fused epilogue (N=11008, K=2048): 256^2, 512 thr, GR=4
  gemm_conv_kernel<256, 256, 512, 4, 4><<<688, 512, 0, stream>>>(hbuf, gu_t, fusebuf, nullptr, 11008, 2048, 2048, 2048);
  // out += fuse @ down^T  (N=2048, K=5504): 128x128 tiles, GR=8 (r16 best)
  gemm_conv_kernel<128, 128, 256, 1, 8><<<512, 256, 0, stream>>>(fusebuf, d_t, out, out, 2048, 5504, 5504, 5504);
}

// Round 24
// 506.288 us; speedup vs baseline: 1.0216x; 1.0216x over previous
//
#include <hip/hip_runtime.h>
#include <cstdint>
#include <cstddef>

typedef unsigned short u16;
typedef __attribute__((ext_vector_type(8))) short short8;
typedef __attribute__((ext_vector_type(4))) float f32x4;

#define DEV __device__ __forceinline__

DEV float bf2f(u16 v) { union { unsigned u; float f; } x; x.u = ((unsigned)v) << 16; return x.f; }
DEV u16 f2bf(float f) {
  union { float f; unsigned u; } x; x.f = f;
  unsigned r = x.u + 0x7fffu + ((x.u >> 16) & 1u);
  return (u16)(r >> 16);
}

DEV void gload_lds16(const void* g, void* l) {
  __builtin_amdgcn_global_load_lds((const __attribute__((address_space(1))) void*)g,
                                   (__attribute__((address_space(3))) void*)l, 16, 0, 0);
}

#define BARRIER __builtin_amdgcn_s_barrier()
#define VM0 asm volatile("s_waitcnt vmcnt(0)" ::: "memory")
#define VM4 asm volatile("s_waitcnt vmcnt(4)" ::: "memory")

// ---------- RMSNorm row body: f32 row (2048) -> bf16 ----------
DEV void rmsnorm_row(const float* __restrict__ x, const float* __restrict__ scale,
                     u16* __restrict__ out, int row, int tid, float* red)
{
  const float* xr = x + (size_t)row * 2048;
  const float4 v0 = *(const float4*)&xr[tid * 8];
  const float4 v1 = *(const float4*)&xr[tid * 8 + 4];
  float ss = v0.x * v0.x + v0.y * v0.y + v0.z * v0.z + v0.w * v0.w +
             v1.x * v1.x + v1.y * v1.y + v1.z * v1.z + v1.w * v1.w;
#pragma unroll
  for (int d = 32; d > 0; d >>= 1) ss += __shfl_down(ss, d);
  if ((tid & 63) == 0) red[tid >> 6] = ss;
  __syncthreads();
  const float tot = red[0] + red[1] + red[2] + red[3];
  const float inv = rsqrtf(tot * (1.f / 2048.f) + 1e-6f);
  const float* sc = scale + tid * 8;
  short8 ov;
  ov[0] = (short)f2bf(v0.x * inv * sc[0]); ov[1] = (short)f2bf(v0.y * inv * sc[1]);
  ov[2] = (short)f2bf(v0.z * inv * sc[2]); ov[3] = (short)f2bf(v0.w * inv * sc[3]);
  ov[4] = (short)f2bf(v1.x * inv * sc[4]); ov[5] = (short)f2bf(v1.y * inv * sc[5]);
  ov[6] = (short)f2bf(v1.z * inv * sc[6]); ov[7] = (short)f2bf(v1.w * inv * sc[7]);
  *(short8*)&out[(size_t)row * 2048 + tid * 8] = ov;
}

// ---------- 64x64 transpose tile: f32 (R x C) -> bf16 (C x R) ----------
// mode 0: row j -> j. mode 1 (gate) / 2 (up): SwiGLU-interleaved row
// (256-row granularity): perm(j) = (j>>7)*256 + ((j>>5)&3)*64 + up*32 + (j&31)
DEV void transpose_tile(const float* __restrict__ in, u16* __restrict__ out,
                        int R, int C, int mode, int bx, int by, int bz,
                        int tid, float (&tile)[64][65])
{
  const int tx = tid & 31, ty = tid >> 5;   // (32, 8)
  const int c0 = bx * 64, r0 = by * 64;
  const float* inb = in + (size_t)bz * R * C;
  u16* outb = out + (size_t)bz * R * C;
#pragma unroll
  for (int i = 0; i < 8; ++i) {
    const int r = ty + i * 8;
    const float2 v = *(const float2*)&inb[(size_t)(r0 + r) * C + c0 + tx * 2];
    tile[r][tx * 2] = v.x;
    tile[r][tx * 2 + 1] = v.y;
  }
  __syncthreads();
#pragma unroll
  for (int i = 0; i < 8; ++i) {
    const int jj = ty + i * 8;
    const int j = c0 + jj;
    const int prow = mode ? ((j >> 7) * 256 + (((j >> 5) & 3) << 6) + ((mode == 2) << 5) + (j & 31))
                          : j;
    const unsigned a = f2bf(tile[tx * 2][jj]);
    const unsigned b = f2bf(tile[tx * 2 + 1][jj]);
    *(unsigned*)&outb[(size_t)prow * R + r0 + tx * 2] = a | (b << 16);
  }
}

// ---------- unified prep: 7 weight transposes + bias concat + rmsnorm(ln1) ----------
// segments (flattened block ranges):
//   [0,1024)      q_w   (2,32,16) -> wqkv_t
//   [1024,1152)   k_w   (2,32,2)  -> wqkv_t + 2048*2048
//   [1152,1280)   v_w   (2,32,2)  -> wqkv_t + 2304*2048
//   [1280,2304)   o_w   (32,32,1) -> o_wt
//   [2304,5056)   gate  (86,32,1) -> gu_t (mode 1)
//   [5056,7808)   up    (86,32,1) -> gu_t (mode 2)
//   [7808,10560)  down  (32,86,1) -> d_t
//   [10560,10570) concat_bias (10 x 256 threads)
//   [10570,14666) rmsnorm ln1: x row (bid-10570) -> hbuf  (independent of above)
__global__ __launch_bounds__(256) void prep_kernel(
    const float* __restrict__ q_w, const float* __restrict__ k_w,
    const float* __restrict__ v_w, const float* __restrict__ o_w,
    const float* __restrict__ gate_w, const float* __restrict__ up_w,
    const float* __restrict__ down_w,
    const float* __restrict__ qb, const float* __restrict__ kb,
    const float* __restrict__ vb,
    const float* __restrict__ x, const float* __restrict__ ln1,
    u16* __restrict__ wqkv_t, u16* __restrict__ o_wt,
    u16* __restrict__ gu_t, u16* __restrict__ d_t, float* __restrict__ bias,
    u16* __restrict__ hbuf)
{
  __shared__ float tile[64][65];
  const int bid = (int)blockIdx.x;
  const int tid = threadIdx.x;
  if (bid < 1024) {
    transpose_tile(q_w, wqkv_t, 2048, 128, 0, bid & 1, (bid >> 1) & 31, bid >> 6, tid, tile);
  } else if (bid < 1152) {
    const int l = bid - 1024;
    transpose_tile(k_w, wqkv_t + 2048LL * 2048, 2048, 128, 0, l & 1, (l >> 1) & 31, l >> 6, tid, tile);
  } else if (bid < 1280) {
    const int l = bid - 1152;
    transpose_tile(v_w, wqkv_t + 2304LL * 2048, 2048, 128, 0, l & 1, (l >> 1) & 31, l >> 6, tid, tile);
  } else if (bid < 2304) {
    const int l = bid - 1280;
    transpose_tile(o_w, o_wt, 2048, 2048, 0, l & 31, l >> 5, 0, tid, tile);
  } else if (bid < 5056) {
    const int l = bid - 2304;
    transpose_tile(gate_w, gu_t, 2048, 5504, 1, l % 86, l / 86, 0, tid, tile);
  } else if (bid < 7808) {
    const int l = bid - 5056;
    transpose_tile(up_w, gu_t, 2048, 5504, 2, l % 86, l / 86, 0, tid, tile);
  } else if (bid < 10560) {
    const int l = bid - 7808;
    transpose_tile(down_w, d_t, 5504, 2048, 0, l & 31, l >> 5, 0, tid, tile);
  } else if (bid < 10570) {
    const int i = (bid - 10560) * 256 + tid;
    if (i < 2048) bias[i] = qb[i];
    else if (i < 2304) bias[i] = kb[i - 2048];
    else if (i < 2560) bias[i] = vb[i - 2304];
  } else {
    rmsnorm_row(x, ln1, hbuf, bid - 10570, tid, &tile[0][0]);
  }
}

// ---------- RMSNorm standalone (ln2) ----------
__global__ __launch_bounds__(256) void rmsnorm_kernel(
    const float* __restrict__ x, const float* __restrict__ scale, u16* __restrict__ out)
{
  __shared__ float red[4];
  rmsnorm_row(x, scale, out, blockIdx.x, threadIdx.x, red);
}

// ---------- GEMM convoy, BK=64, TB threads (2M x (BN/64)N waves) ----------
// C(4096 x N) = A(4096 x K, lda) @ Bt(N x K, ldb)^T
// ONE barrier per K-tile (r15). A dbuf, B triple-buf, counted vmcnt(4); no
// explicit lgkm drain. Block order: XCD-chunked, then L2 super-tiled --
// row-groups of GR swept across all cols: rg=id%GR, c=(id/GR)%ncol.
// 16x16x32 MFMA (32x32 fragments break the 8-slot swizzle: 4-way conflicts, r19).
// Swizzle: granule slot = g ^ (row&7); linear LDS dest + inv-swz source.
// MODE 0: f32+bias[col]; 1: f32+aux[idx]; 2: bf16; 3: bf16+bias[col];
// MODE 4 (BM=256): SwiGLU-fused epilogue -> bf16 [4096 x N/2], ld = N/2.
template <int BM, int BN, int TB, int MODE, int GR>
__global__ __launch_bounds__(TB, 512 / TB) void gemm_conv_kernel(
    const u16* __restrict__ A, const u16* __restrict__ Bt,
    void* C, const float* __restrict__ aux, int N, int K, int lda, int ldb)
{
  constexpr int MFRAG = BM / 32;    // per-wave M fragments (wave covers BM/2 rows)
  constexpr int AISS = BM * 8 / TB; // A stage issues per thread
  constexpr int BISS = BN * 8 / TB; // B stage issues per thread (=4 everywhere)
  constexpr int WN = BN / 64;
  __shared__ __align__(16) u16 As[2][BM * 64];
  __shared__ __align__(16) u16 Bs[3][BN * 64];

  const int tid = threadIdx.x;
  const int wv = tid >> 6, lane = tid & 63, lo = lane & 15, hi = lane >> 4;
  const int wm = wv / WN, wn = wv % WN;

  const int nwg = (int)gridDim.x;           // multiple of 8
  const int id0 = (int)blockIdx.x;
  const int id = (id0 & 7) * (nwg >> 3) + (id0 >> 3);   // XCD-chunked
  const int ncol = N / BN;
  const int rg = id % GR, cc = (id / GR) % ncol, gg = id / (GR * ncol);
  const int by = gg * GR + rg, bx = cc;
  const int row0 = by * BM, col0 = bx * BN;

  const f32x4 fz = {0.f, 0.f, 0.f, 0.f};
  f32x4 acc[MFRAG][4];
#pragma unroll
  for (int m = 0; m < MFRAG; ++m)
#pragma unroll
    for (int n = 0; n < 4; ++n) acc[m][n] = fz;

  const int nt = K >> 6;

  auto STAGE_A = [&](int kt, int ab) {
#pragma unroll
    for (int i = 0; i < AISS; ++i) {
      const int f = i * TB + tid;
      const int rp = f >> 3, sp = tid & 7;
      gload_lds16(A + (size_t)(row0 + rp) * lda + kt * 64 + ((sp ^ (rp & 7)) * 8),
                  (char*)&As[ab][0] + (i * TB + wv * 64) * 16);
    }
  };
  auto STAGE_B = [&](int kt, int bb) {
#pragma unroll
    for (int i = 0; i < BISS; ++i) {
      const int f = i * TB + tid;
      const int rp = f >> 3, sp = tid & 7;
      gload_lds16(Bt + (size_t)(col0 + rp) * ldb + kt * 64 + ((sp ^ (rp & 7)) * 8),
                  (char*)&Bs[bb][0] + (i * TB + wv * 64) * 16);
    }
  };

#define LDA8M(ARR, BUF, S, G)                                                    \
  _Pragma("unroll")                                                              \
  for (int mt = 0; mt < 4; ++mt) {                                               \
    const int r = wm * (BM / 2) + ((G) * 4 + mt) * 16 + lo;                      \
    ARR[mt] = *(const short8*)&As[BUF][r * 64 + (((S) * 4 + hi) ^ (r & 7)) * 8]; \
  }
#define LDB8M(ARR, BUF, S)                                                       \
  _Pragma("unroll")                                                              \
  for (int nn = 0; nn < 4; ++nn) {                                               \
    const int r = wn * 64 + nn * 16 + lo;                                        \
    ARR[nn] = *(const short8*)&Bs[BUF][r * 64 + (((S) * 4 + hi) ^ (r & 7)) * 8]; \
  }
#define MFMA16M(AR, BR, G)                                                       \
  __builtin_amdgcn_s_setprio(1);                                                 \
  _Pragma("unroll")                                                              \
  for (int mt = 0; mt < 4; ++mt)                                                 \
    _Pragma("unroll")                                                            \
    for (int nn = 0; nn < 4; ++nn)                                               \
      acc[(G) * 4 + mt][nn] = __builtin_amdgcn_mfma_f32_16x16x32_bf16(           \
          AR[mt], BR[nn], acc[(G) * 4 + mt][nn], 0, 0, 0);                       \
  __builtin_amdgcn_s_setprio(0);

  // prologue: A(0), B(0), B(1); counted drain leaves B(1) in flight
  STAGE_A(0, 0); STAGE_B(0, 0); STAGE_B(1, 1);
  VM4; BARRIER;

  int ab = 0, bcur = 0;
  for (int t = 0; t < nt; ++t) {
    const bool preA = (t + 1 < nt);
    const bool preB = (t + 2 < nt);
    const int bs2 = (bcur >= 1) ? bcur - 1 : 2;   // (t+2) % 3
    if constexpr (BM == 256) {
      short8 a0[4], a1[4], b0[4], a2[4], a3[4], b1[4];
      LDA8M(a0, ab, 0, 0); LDA8M(a1, ab, 0, 1); LDB8M(b0, bcur, 0);
      LDA8M(a2, ab, 1, 0); LDA8M(a3, ab, 1, 1); LDB8M(b1, bcur, 1);
      if (preA) STAGE_A(t + 1, ab ^ 1);
      if (preB) STAGE_B(t + 2, bs2);
      MFMA16M(a0, b0, 0); MFMA16M(a1, b0, 1);
      MFMA16M(a2, b1, 0); MFMA16M(a3, b1, 1);
      if (preA) { if (preB) VM4; else VM0; }
      BARRIER;
    } else {
      short8 a0[4], b0[4], a1[4], b1[4];
      LDA8M(a0, ab, 0, 0); LDB8M(b0, bcur, 0);
      LDA8M(a1, ab, 1, 0); LDB8M(b1, bcur, 1);
      if (preA) STAGE_A(t + 1, ab ^ 1);
      if (preB) STAGE_B(t + 2, bs2);
      MFMA16M(a0, b0, 0);
      MFMA16M(a1, b1, 0);
      if (preA) { if (preB) VM4; else VM0; }
      BARRIER;
    }
    ab ^= 1;
    bcur = (bcur == 2) ? 0 : bcur + 1;
  }
#undef LDA8M
#undef LDB8M
#undef MFMA16M

  float* Cf = (float*)C;
  u16* Ch = (u16*)C;
  if constexpr (MODE == 4) {
    const int ldo = N >> 1;   // 5504
#pragma unroll
    for (int fm = 0; fm < MFRAG; ++fm) {
#pragma unroll
      for (int nn = 0; nn < 2; ++nn) {
        const int fcol = (col0 >> 1) + wn * 32 + nn * 16 + lo;
#pragma unroll
        for (int j = 0; j < 4; ++j) {
          const int row = row0 + wm * (BM / 2) + fm * 16 + hi * 4 + j;
          const float g = acc[fm][nn][j];
          const float u = acc[fm][nn + 2][j];
          const float sg = g / (1.f + __builtin_amdgcn_exp2f(-1.4426950408889634f * g));
          Ch[(size_t)row * ldo + fcol] = f2bf(sg * u);
        }
      }
    }
  } else {
#pragma unroll
    for (int fm = 0; fm < MFRAG; ++fm) {
#pragma unroll
      for (int nn = 0; nn < 4; ++nn) {
        const int col = col0 + wn * 64 + nn * 16 + lo;
#pragma unroll
        for (int j = 0; j < 4; ++j) {
          const int row = row0 + wm * (BM / 2) + fm * 16 + hi * 4 + j;
          const size_t idx = (size_t)row * N + col;
          const float v = acc[fm][nn][j];
          if (MODE == 0) Cf[idx] = v + aux[col];
          else if (MODE == 1) Cf[idx] = v + aux[idx];
          else if (MODE == 2) Ch[idx] = f2bf(v);
          else Ch[idx] = f2bf(v + aux[col]);
        }
      }
    }
  }
}

// ---------- fused RoPE q/k + V transpose: qkv bf16 (4096 x 2560) ----------
// per row: 1024 q-threads (2 elems each), 128 k-threads, 256 v-threads = 1408
// q scale = 1/sqrt(128) * log2(e)  (softmax done in exp2 domain)
__global__ __launch_bounds__(256) void rope_qkv_kernel(
    const u16* __restrict__ qkv, const int* __restrict__ pos,
    u16* __restrict__ Qb, u16* __restrict__ Kb, u16* __restrict__ Vt)
{
  const int idx = blockIdx.x * 256 + threadIdx.x;  // 4096*1408
  const int bt = idx / 1408;
  const int r = idx - bt * 1408;
  const int t = bt & 2047, b = bt >> 11;
  if (r < 1152) {
    const bool isq = r < 1024;
    const int rr = isq ? r : r - 1024;
    const int n = rr >> 6, hp = rr & 63;
    const u16* q = qkv + (size_t)bt * 2560 + (isq ? 0 : 2048) + n * 128 + hp;
    const float x1 = bf2f(q[0]);
    const float x2 = bf2f(q[64]);
    const float inv = exp2f((float)hp * (-19.931568569324174f / 64.f));
    const float ang = (float)pos[t] * inv;
    float s, c;
    sincosf(ang, &s, &c);
    const float sc = isq ? 0.08838834764831845f * 1.4426950408889634f : 1.f;
    const size_t base = isq ? (((size_t)(b * 16 + n) * 2048 + t) * 128 + hp)
                            : (((size_t)(b * 2 + n) * 2048 + t) * 128 + hp);
    u16* outp = isq ? Qb : Kb;
    outp[base] = f2bf((x1 * c - x2 * s) * sc);
    outp[base + 64] = f2bf((x2 * c + x1 * s) * sc);
  } else {
    const int rr = r - 1152;
    const int kh = rr >> 7, hh = rr & 127;
    Vt[((size_t)((b * 2 + kh) * 128 + hh)) * 2048 + t] =
        qkv[(size_t)bt * 2560 + 2304 + kh * 128 + hh];
  }
}

// ---------- flash attention, causal, GQA group 8 ----------
// 8 waves / 512 threads, Q-tile = 128 rows, KV-tile = 128 rows. LDS 160 KiB.
// Grid (bn=32, pair=8): all 8 pair-blocks of one head on one XCD (T1).
__global__ __launch_bounds__(512) void attn_kernel(
    const u16* __restrict__ Qb, const u16* __restrict__ Kb,
    const u16* __restrict__ Vt, u16* __restrict__ Out)
{
  __shared__ u16 Ks[2][128 * 128];   // 64 KB
  __shared__ u16 Vs[2][128 * 128];   // 64 KB
  __shared__ u16 Ps[8][16 * 128];    // 32 KB
  const int tid = threadIdx.x;
  const int wave = tid >> 6, lane = tid & 63, lo = lane & 15, hi = lane >> 4;
  const int bn = blockIdx.x;
  const int b = bn >> 4, n = bn & 15, kh = n >> 3;

  const f32x4 fz = {0.f, 0.f, 0.f, 0.f};
  const u16* kg = Kb + (size_t)(b * 2 + kh) * 2048 * 128;
  const u16* vg = Vt + (size_t)(b * 2 + kh) * 128 * 2048;

  auto STAGE = [&](int buf, int s0) {
#pragma unroll
    for (int i = 0; i < 4; ++i) {
      const int gk = i * 512 + tid;          // 2048 granules = 128 rows x 16
      const int rk = gk >> 4, gck = gk & 15;
      gload_lds16(kg + (size_t)(s0 + rk) * 128 + ((gck ^ (rk & 7)) * 8),
                  (char*)&Ks[buf][0] + (i * 512 + wave * 64) * 16);
      gload_lds16(vg + (size_t)rk * 2048 + s0 + ((gck ^ (rk & 7)) * 8),
                  (char*)&Vs[buf][0] + (i * 512 + wave * 64) * 16);
    }
  };

  auto processTile = [&](int q0) {
    const int nblk = q0 / 128 + 1;   // KV tiles of 128 covering [0, q0+128)
    const u16* qptr = Qb + ((size_t)((b * 16 + n) * 2048) + q0 + wave * 16 + lo) * 128;
    short8 qf[4];
#pragma unroll
    for (int kc = 0; kc < 4; ++kc) qf[kc] = *(const short8*)&qptr[kc * 32 + hi * 8];

    float m_r[4], l_r[4];
    f32x4 oacc[8];
#pragma unroll
    for (int j = 0; j < 4; ++j) { m_r[j] = -1e30f; l_r[j] = 0.f; }
#pragma unroll
    for (int ht = 0; ht < 8; ++ht) oacc[ht] = fz;

    __syncthreads();
    STAGE(0, 0);
    __syncthreads();

    int cur = 0;
    for (int sb = 0; sb < nblk; ++sb) {
      const int s0 = sb * 128;
      if (sb + 1 < nblk) STAGE(cur ^ 1, s0 + 128);

      float sall[8][4];
      __builtin_amdgcn_s_setprio(1);
#pragma unroll
      for (int st = 0; st < 8; ++st) {
        f32x4 s = fz;
#pragma unroll
        for (int kc = 0; kc < 4; ++kc) {
          const int row = st * 16 + lo;
          const int cb = (kc * 64 + hi * 16) ^ ((lo & 7) << 4);
          short8 kf = *(const short8*)&Ks[cur][row * 128 + (cb >> 1)];
          s = __builtin_amdgcn_mfma_f32_16x16x32_bf16(qf[kc], kf, s, 0, 0, 0);
        }
#pragma unroll
        for (int j = 0; j < 4; ++j) sall[st][j] = s[j];
      }
      __builtin_amdgcn_s_setprio(0);

      if (s0 + 128 > q0) {   // only the final tile needs the causal mask
#pragma unroll
        for (int st = 0; st < 8; ++st) {
          const int sg = s0 + st * 16 + lo;
#pragma unroll
          for (int j = 0; j < 4; ++j) {
            const int qg = q0 + wave * 16 + hi * 4 + j;
            if (sg > qg) sall[st][j] = -1e30f;
          }
        }
      }

      float tmax[4];
#pragma unroll
      for (int j = 0; j < 4; ++j) {
        float t = fmaxf(fmaxf(fmaxf(sall[0][j], sall[1][j]), fmaxf(sall[2][j], sall[3][j])),
                        fmaxf(fmaxf(sall[4][j], sall[5][j]), fmaxf(sall[6][j], sall[7][j])));
        t = fmaxf(t, __shfl_xor(t, 1));
        t = fmaxf(t, __shfl_xor(t, 2));
        t = fmaxf(t, __shfl_xor(t, 4));
        t = fmaxf(t, __shfl_xor(t, 8));
        tmax[j] = t;
      }
      const bool defer = __all((tmax[0] - m_r[0] <= 8.f) & (tmax[1] - m_r[1] <= 8.f) &
                               (tmax[2] - m_r[2] <= 8.f) & (tmax[3] - m_r[3] <= 8.f));
      if (!defer) {
        float alpha[4];
#pragma unroll
        for (int j = 0; j < 4; ++j) {
          const float mnew = fmaxf(m_r[j], tmax[j]);
          alpha[j] = __builtin_amdgcn_exp2f(m_r[j] - mnew);
          m_r[j] = mnew;
          l_r[j] *= alpha[j];
        }
#pragma unroll
        for (int ht = 0; ht < 8; ++ht) {
#pragma unroll
          for (int j = 0; j < 4; ++j) oacc[ht][j] *= alpha[j];
        }
      }

      float rsum[4] = {0.f, 0.f, 0.f, 0.f};
#pragma unroll
      for (int st = 0; st < 8; ++st) {
#pragma unroll
        for (int j = 0; j < 4; ++j) {
          const float p = __builtin_amdgcn_exp2f(sall[st][j] - m_r[j]);
          rsum[j] += p;
          const int row = hi * 4 + j;
          const int cbp = (st * 32 + lo * 2) ^ ((row & 7) << 4);
          Ps[wave][row * 128 + (cbp >> 1)] = f2bf(p);
        }
      }
#pragma unroll
      for (int j = 0; j < 4; ++j) {
        float rs = rsum[j];
        rs += __shfl_xor(rs, 1);
        rs += __shfl_xor(rs, 2);
        rs += __shfl_xor(rs, 4);
        rs += __shfl_xor(rs, 8);
        l_r[j] += rs;
      }

      asm volatile("s_waitcnt lgkmcnt(0)" ::: "memory");
      __builtin_amdgcn_sched_barrier(0);

      short8 pf[4];
#pragma unroll
      for (int s = 0; s < 4; ++s) {
        const int pcb = (s * 64 + hi * 16) ^ ((lo & 7) << 4);
        pf[s] = *(const short8*)&Ps[wave][lo * 128 + (pcb >> 1)];
      }
      __builtin_amdgcn_s_setprio(1);
#pragma unroll
      for (int ht = 0; ht < 8; ++ht) {
        const int row = ht * 16 + lo;
#pragma unroll
        for (int s = 0; s < 4; ++s) {
          const int cb = (s * 64 + hi * 16) ^ ((row & 7) << 4);
          const short8 vf = *(const short8*)&Vs[cur][row * 128 + (cb >> 1)];
          oacc[ht] = __builtin_amdgcn_mfma_f32_16x16x32_bf16(pf[s], vf, oacc[ht], 0, 0, 0);
        }
      }
      __builtin_amdgcn_s_setprio(0);

      if (sb + 1 < nblk) __syncthreads();
      cur ^= 1;
    }

#pragma unroll
    for (int j = 0; j < 4; ++j) {
      const float inv = 1.0f / l_r[j];
      const int trow = q0 + wave * 16 + hi * 4 + j;
      const size_t base = ((size_t)(b * 2048 + trow)) * 2048 + n * 128;
#pragma unroll
      for (int ht = 0; ht < 8; ++ht)
        Out[base + ht * 16 + lo] = f2bf(oacc[ht][j] * inv);
    }
  };

  processTile((int)(15 - blockIdx.y) * 128);
  processTile((int)blockIdx.y * 128);
}

extern "C" void kernel_launch(void* const* d_in, const int* in_sizes, int n_in,
                              void* d_out, int out_size, void* d_ws, size_t ws_size,
                              hipStream_t stream)
{
  const float* x      = (const float*)d_in[0];
  const int*   pos    = (const int*)d_in[1];
  const float* ln1    = (const float*)d_in[2];
  const float* q_w    = (const float*)d_in[3];
  const float* q_b    = (const float*)d_in[4];
  const float* k_w    = (const float*)d_in[5];
  const float* k_b    = (const float*)d_in[6];
  const float* v_w    = (const float*)d_in[7];
  const float* v_b    = (const float*)d_in[8];
  const float* o_w    = (const float*)d_in[9];
  const float* ln2    = (const float*)d_in[10];
  const float* gate_w = (const float*)d_in[11];
  const float* up_w   = (const float*)d_in[12];
  const float* down_w = (const float*)d_in[13];
  float* out = (float*)d_out;

  char* w = (char*)d_ws;
  u16* wqkv_t = (u16*)w;       w += 2560LL * 2048 * 2;   // (N*H+KH*H*2) x D, bf16
  u16* o_wt   = (u16*)w;       w += 2048LL * 2048 * 2;   // D x (N*H)
  u16* gu_t   = (u16*)w;       w += 11008LL * 2048 * 2;  // SwiGLU-interleaved [gate|up]
  u16* d_t    = (u16*)w;       w += 2048LL * 5504 * 2;   // D x I
  u16* hbuf   = (u16*)w;       w += 4096LL * 2048 * 2;   // h / h2 bf16
  float* bias_qkv = (float*)w; w += 2560 * 4;
  char* un = w;  // union region: phase1 (qkv/Qb/Kb/Vt/attn) then phase2 (fuse)
  u16*  qkv   = (u16*)un;                                              // 4096x2560 bf16
  u16*  Qb    = (u16*)(un + 41943040LL);                               // (B,N,T,H)
  u16*  Kb    = (u16*)(un + 41943040LL + 16777216LL);                  // (B,KH,T,H)
  u16*  Vt    = (u16*)(un + 41943040LL + 16777216LL + 2097152LL);      // (B,KH,H,T)
  u16*  attnb = (u16*)(un + 41943040LL + 16777216LL + 2097152LL + 2097152LL); // (B,T,N*H)
  u16*  fusebuf = (u16*)un;                                            // 4096x5504 bf16

  // unified prep: weight transposes + bias concat + rmsnorm(ln1), one launch
  prep_kernel<<<14666, 256, 0, stream>>>(q_w, k_w, v_w, o_w, gate_w, up_w, down_w,
                                         q_b, k_b, v_b, x, ln1,
                                         wqkv_t, o_wt, gu_t, d_t, bias_qkv, hbuf);

  // qkv = h @ Wqkv^T + bias -> bf16  (N=2560, K=2048): 128x128 tiles, GR=8
  gemm_conv_kernel<128, 128, 256, 3, 8><<<640, 256, 0, stream>>>(hbuf, wqkv_t, qkv, bias_qkv, 2560, 2048, 2048, 2048);
  // fused rope q/k + V transpose (1408 threads per (b,t) row)
  rope_qkv_kernel<<<22528, 256, 0, stream>>>(qkv, pos, Qb, Kb, Vt);
  // attention: grid (bn=32, pair=8), KV-tile = 128 rows, LDS 160 KiB
  attn_kernel<<<dim3(32, 8), 512, 0, stream>>>(Qb, Kb, Vt, attnb);
  // res = attn @ o_w^T + x -> out (f32): 128x128 tiles, GR=8 (K=2048)
  gemm_conv_kernel<128, 128, 256, 1, 8><<<512, 256, 0, stream>>>(attnb, o_wt, out, x, 2048, 2048, 2048, 2048);
  // ln2 -> h2 (reuse hbuf)
  rmsnorm_kernel<<<4096, 256, 0, stream>>>(out, ln2, hbuf);
  // gate+up merged + SwiGLU-fused epilogue (N=11008, K=2048): 256^2, 512 thr, GR=4
  gemm_conv_kernel<256, 256, 512, 4, 4><<<688, 512, 0, stream>>>(hbuf, gu_t, fusebuf, nullptr, 11008, 2048, 2048, 2048);
  // out += fuse @ down^T  (N=2048, K=5504): 128x128 tiles, GR=8 (r16 best)
  gemm_conv_kernel<128, 128, 256, 1, 8><<<512, 256, 0, stream>>>(fusebuf, d_t, out, out, 2048, 5504, 5504, 5504);
}